// Round 10
// baseline (489.691 us; speedup 1.0000x reference)
//
#include <hip/hip_runtime.h>
#include <stdint.h>

typedef __attribute__((ext_vector_type(8))) short bf16x8;   // 8 bf16 = 4 VGPR (MFMA A/B frag)
typedef __attribute__((ext_vector_type(4))) float f32x4;    // MFMA C/D frag
typedef __attribute__((ext_vector_type(4))) unsigned short us4;
typedef __attribute__((ext_vector_type(8))) unsigned short us8;

__device__ __forceinline__ unsigned short f2bf(float f) {   // RNE f32 -> bf16
  union { float f; unsigned u; } x; x.f = f;
  unsigned r = x.u + 0x7FFFu + ((x.u >> 16) & 1u);
  return (unsigned short)(r >> 16);
}
__device__ __forceinline__ float bf2f(unsigned short h) {
  union { unsigned u; float f; } x; x.u = ((unsigned)h) << 16;
  return x.f;
}

// async global->LDS, 16B per lane; LDS dest is wave-uniform base + lane*16
#define GL2LDS(g, l) __builtin_amdgcn_global_load_lds( \
    (const __attribute__((address_space(1))) unsigned int*)(g), \
    (__attribute__((address_space(3))) unsigned int*)(l), 16, 0, 0)

// raw barrier with compiler memory fence (no vmcnt/lgkm drain at runtime)
#define BARRIER() do { asm volatile("" ::: "memory"); \
  __builtin_amdgcn_s_barrier(); asm volatile("" ::: "memory"); } while (0)
#define SCHED0() __builtin_amdgcn_sched_barrier(0)

// ---------------- fused prep (unchanged) ----------------
__global__ __launch_bounds__(256)
void prep(const float* __restrict__ x,
          const float* __restrict__ wq, const float* __restrict__ wk,
          const float* __restrict__ wv, const float* __restrict__ wo,
          unsigned short* __restrict__ xb,
          unsigned short* __restrict__ wqb, unsigned short* __restrict__ wkb,
          unsigned short* __restrict__ vtb, unsigned short* __restrict__ opT)
{
  __shared__ float t[32][33];
  const int b = blockIdx.x;
  if (b < 10240) {
    const float* in; unsigned short* out; int i;
    if (b < 8192)      { in = x;  out = xb;  i = b * 256 + threadIdx.x; }
    else if (b < 9216) { in = wq; out = wqb; i = (b - 8192) * 256 + threadIdx.x; }
    else               { in = wk; out = wkb; i = (b - 9216) * 256 + threadIdx.x; }
    const float4 f = ((const float4*)in)[i];
    us4 v;
    v[0] = f2bf(f.x); v[1] = f2bf(f.y); v[2] = f2bf(f.z); v[3] = f2bf(f.w);
    ((us4*)out)[i] = v;
  } else {
    const float* in = (b < 11264) ? wv : wo;
    unsigned short* out = (b < 11264) ? vtb : opT;
    const int tb = (b < 11264) ? (b - 10240) : (b - 11264);
    const int bx = (tb & 31) * 32, by = (tb >> 5) * 32;
    const int tx = threadIdx.x & 31, ty = threadIdx.x >> 5;
#pragma unroll
    for (int i = 0; i < 32; i += 8)
      t[ty + i][tx] = in[(size_t)(by + ty + i) * 1024 + bx + tx];
    __syncthreads();
#pragma unroll
    for (int i = 0; i < 32; i += 8)
      out[(size_t)(bx + ty + i) * 1024 + by + tx] = f2bf(t[tx][ty + i]);
  }
}

// ======== m201-faithful 256x256 8-phase K-loop (BK=64, 512 thr / 8 waves) ====
// (unchanged — ~950 TF in-block measured at K=1024)
__device__ __forceinline__ void kloop8p(
    const unsigned short* __restrict__ Ag, const unsigned short* __restrict__ Bg,
    const int lda, const int ldw, const int NT,   // NT = K/64, even, >= 2
    char* smem, f32x4 (&acc)[8][4])
{
  const int tid = threadIdx.x;
  const int lane = tid & 63, wave = tid >> 6;
  const int quad = lane >> 4, l16 = lane & 15;
  const int wm = wave >> 2, wn = wave & 3;

  const int c0 = (quad * 16) ^ ((l16 & 7) << 4);   // swizzled ks=0 byte col
  const int aR = (wm * 64 + l16) * 128;            // byte row base in A-half
  const int bR = (wn * 32 + l16) * 128;            // byte row base in B-half

  const int scol = ((tid & 7) ^ ((tid >> 3) & 7)) << 3;   // inv-swizzled elem col
  const unsigned short* As = Ag + (size_t)(tid >> 3) * lda + scol;
  const unsigned short* Bs = Bg + (size_t)(tid >> 3) * ldw + scol;

#define SA(buf, mh, kt) do { \
    GL2LDS(As + (size_t)((mh) * 128) * lda + (kt) * 64,      smem + (buf) * 65536 + (mh) * 16384 +        tid * 16); \
    GL2LDS(As + (size_t)((mh) * 128 + 64) * lda + (kt) * 64, smem + (buf) * 65536 + (mh) * 16384 + 8192 + tid * 16); } while (0)
#define SB(buf, nh, kt) do { \
    GL2LDS(Bs + (size_t)((nh) * 128) * ldw + (kt) * 64,      smem + (buf) * 65536 + 32768 + (nh) * 16384 +        tid * 16); \
    GL2LDS(Bs + (size_t)((nh) * 128 + 64) * ldw + (kt) * 64, smem + (buf) * 65536 + 32768 + (nh) * 16384 + 8192 + tid * 16); } while (0)
#define RA(buf, mh) do { _Pragma("unroll") for (int fi = 0; fi < 4; ++fi) { \
    afr[fi][0] = *(const bf16x8*)(smem + (buf) * 65536 + (mh) * 16384 + aR + fi * 2048 + c0); \
    afr[fi][1] = *(const bf16x8*)(smem + (buf) * 65536 + (mh) * 16384 + aR + fi * 2048 + (c0 ^ 64)); } } while (0)
#define RB(buf, nh, bb) do { _Pragma("unroll") for (int fj = 0; fj < 2; ++fj) { \
    bb[fj][0] = *(const bf16x8*)(smem + (buf) * 65536 + 32768 + (nh) * 16384 + bR + fj * 2048 + c0); \
    bb[fj][1] = *(const bf16x8*)(smem + (buf) * 65536 + 32768 + (nh) * 16384 + bR + fj * 2048 + (c0 ^ 64)); } } while (0)
#define MM(mh, nh, bb) do { __builtin_amdgcn_s_setprio(1); \
    _Pragma("unroll") for (int fi = 0; fi < 4; ++fi) \
    _Pragma("unroll") for (int fj = 0; fj < 2; ++fj) \
    _Pragma("unroll") for (int ks = 0; ks < 2; ++ks) \
      acc[(mh) * 4 + fi][(nh) * 2 + fj] = __builtin_amdgcn_mfma_f32_16x16x32_bf16( \
          afr[fi][ks], bb[fj][ks], acc[(mh) * 4 + fi][(nh) * 2 + fj], 0, 0, 0); \
    __builtin_amdgcn_s_setprio(0); } while (0)

  bf16x8 afr[4][2], b0[2][2], b1[2][2];

  // prologue: tile0 full (8 loads) + tile1 {Ah0, Bh1} (4 loads)
  SA(0, 0, 0); SA(0, 1, 0); SB(0, 0, 0); SB(0, 1, 0);
  SA(1, 0, 1); SB(1, 1, 1);
  asm volatile("s_waitcnt vmcnt(4)" ::: "memory");
  __builtin_amdgcn_s_barrier();

  for (int t = 0; t < NT; t += 2) {
    const bool s2 = (t + 2 < NT), s3 = (t + 3 < NT);

    // ---- p1: tile t, quadrant (0,0)
    RA(0, 0); RB(0, 0, b0);
    SA(1, 1, t + 1);
    BARRIER(); SCHED0(); MM(0, 0, b0); SCHED0(); BARRIER();
    // ---- p2: (0,1)
    RB(0, 1, b1);
    SB(1, 0, t + 1);
    BARRIER(); SCHED0(); MM(0, 1, b1); SCHED0(); BARRIER();
    // ---- p3: (1,1)
    RA(0, 1);
    if (s2) SA(0, 0, t + 2);
    BARRIER(); SCHED0(); MM(1, 1, b1); SCHED0(); BARRIER();
    // ---- p4: (1,0) + gate
    if (s2) SB(0, 1, t + 2);
    BARRIER(); SCHED0(); MM(1, 0, b0);
    if (s2) { asm volatile("s_waitcnt vmcnt(4)" ::: "memory"); }
    else    { asm volatile("s_waitcnt vmcnt(0)" ::: "memory"); }
    SCHED0(); BARRIER();

    // ---- p5: tile t+1, quadrant (0,0)
    RA(1, 0); RB(1, 0, b0);
    if (s2) SA(0, 1, t + 2);
    BARRIER(); SCHED0(); MM(0, 0, b0); SCHED0(); BARRIER();
    // ---- p6: (0,1)
    RB(1, 1, b1);
    if (s2) SB(0, 0, t + 2);
    BARRIER(); SCHED0(); MM(0, 1, b1); SCHED0(); BARRIER();
    // ---- p7: (1,1)
    RA(1, 1);
    if (s3) SA(1, 0, t + 3);
    BARRIER(); SCHED0(); MM(1, 1, b1); SCHED0(); BARRIER();
    // ---- p8: (1,0) + gate
    if (s3) SB(1, 1, t + 3);
    BARRIER(); SCHED0(); MM(1, 0, b0);
    if (s3) { asm volatile("s_waitcnt vmcnt(4)" ::: "memory"); }
    else    { asm volatile("s_waitcnt vmcnt(0)" ::: "memory"); }
    SCHED0(); BARRIER();
  }
#undef SA
#undef SB
#undef RA
#undef RB
#undef MM
}

// ---------------- epilogues (2M x 4N 256^2 layout) ----------------
__device__ __forceinline__ void epi_bf16(const f32x4 (&acc)[8][4], unsigned short* __restrict__ C,
                                         int ldc, int m0, int n0, char* smem)
{
  const int tid = threadIdx.x, lane = tid & 63, wave = tid >> 6;
  const int quad = lane >> 4, l16 = lane & 15;
  const int wm = wave >> 2, wn = wave & 3;
  unsigned short* patch = (unsigned short*)smem + wave * (16 * 72);
#pragma unroll
  for (int mf = 0; mf < 8; ++mf) {
#pragma unroll
    for (int an = 0; an < 4; ++an)
#pragma unroll
      for (int r = 0; r < 4; ++r)
        patch[(quad * 4 + r) * 72 + an * 16 + l16] = f2bf(acc[mf][an][r]);
    __builtin_amdgcn_wave_barrier();
    const int grow0 = m0 + (mf >> 2) * 128 + wm * 64 + (mf & 3) * 16;
#pragma unroll
    for (int it = 0; it < 2; ++it) {
      const int rr = it * 8 + (lane >> 3);
      const int cp = (lane & 7) * 8;
      us8 v = *(const us8*)&patch[rr * 72 + cp];
      const int gcol = n0 + (cp >> 5) * 128 + wn * 32 + (cp & 31);
      *(us8*)&C[(size_t)(grow0 + rr) * ldc + gcol] = v;
    }
    __builtin_amdgcn_wave_barrier();
  }
}

__device__ __forceinline__ void epi_f32(const f32x4 (&acc)[8][4], float* __restrict__ C,
                                        int ldc, int m0, int n0, char* smem)
{
  const int tid = threadIdx.x, lane = tid & 63, wave = tid >> 6;
  const int quad = lane >> 4, l16 = lane & 15;
  const int wm = wave >> 2, wn = wave & 3;
  float* patch = (float*)smem + wave * (16 * 68);
#pragma unroll
  for (int mf = 0; mf < 8; ++mf) {
#pragma unroll
    for (int an = 0; an < 4; ++an)
#pragma unroll
      for (int r = 0; r < 4; ++r)
        patch[(quad * 4 + r) * 68 + an * 16 + l16] = acc[mf][an][r];
    __builtin_amdgcn_wave_barrier();
    const int grow0 = m0 + (mf >> 2) * 128 + wm * 64 + (mf & 3) * 16;
#pragma unroll
    for (int j = 0; j < 4; ++j) {
      const int rr = j * 4 + (lane >> 4);
      const int cp = (lane & 15) * 4;
      float4 v = *(const float4*)&patch[rr * 68 + cp];
      const int gcol = n0 + (cp >> 5) * 128 + wn * 32 + (cp & 31);
      *(float4*)&C[(size_t)(grow0 + rr) * ldc + gcol] = v;
    }
    __builtin_amdgcn_wave_barrier();
  }
}

// ---------------- work-item helpers (bodies unchanged from round 9) ----------
__device__ __forceinline__ void do_qk(int idx, const unsigned short* __restrict__ xb,
    const unsigned short* __restrict__ wqb, const unsigned short* __restrict__ wkb,
    unsigned short* __restrict__ Q, unsigned short* __restrict__ Kb, char* smem)
{
  const int sw = (idx & 7) * 32 + (idx >> 3);   // bijective XCD swizzle over 256
  const int wsel = sw >> 7;                     // 0:Q 1:K
  const int t = sw & 127;
  const int m0 = (t >> 2) * 256, n0 = (t & 3) * 256;
  f32x4 acc[8][4] = {};
  kloop8p(xb + (size_t)m0 * 1024, (wsel ? wkb : wqb) + (size_t)n0 * 1024,
          1024, 1024, 16, smem, acc);
  __syncthreads();
  epi_bf16(acc, wsel ? Kb : Q, 1024, m0, n0, smem);
}

__device__ __forceinline__ void do_vp(int idx, const unsigned short* __restrict__ xb,
    const unsigned short* __restrict__ wctb, unsigned short* __restrict__ VT, char* smem)
{
  const int m0 = (idx >> 2) * 256, n0 = (idx & 3) * 256;
  f32x4 acc[8][4] = {};
  kloop8p(xb + (size_t)m0 * 1024, wctb + (size_t)n0 * 1024, 1024, 1024, 16, smem, acc);
  __syncthreads();
  const int tid = threadIdx.x;
  const int lane = tid & 63, wave = tid >> 6;
  const int quad = lane >> 4, l16 = lane & 15;
  const int wm = wave >> 2, wn = wave & 3;
  unsigned short* patch = (unsigned short*)smem;            // [256][38]
  const int bz = m0 >> 11, sbase = m0 & 2047;
  unsigned short* VTb = VT + (size_t)bz * (1024 * 2048);
  const int colw = tid >> 1, g = tid & 1;
#pragma unroll
  for (int mf = 0; mf < 8; ++mf) {
#pragma unroll
    for (int an = 0; an < 4; ++an) {
      const int col = (an >> 1) * 128 + wn * 32 + (an & 1) * 16 + l16;
#pragma unroll
      for (int r = 0; r < 4; ++r)
        patch[col * 38 + wm * 16 + quad * 4 + r] = f2bf(acc[mf][an][r]);
    }
    __syncthreads();
    const int s0 = sbase + (mf >> 2) * 128 + (mf & 3) * 16 + g * 64;
    us8 v0 = *(const us8*)&patch[colw * 38 + g * 16];
    us8 v1 = *(const us8*)&patch[colw * 38 + g * 16 + 8];
    *(us8*)&VTb[(size_t)(n0 + colw) * 2048 + s0]     = v0;
    *(us8*)&VTb[(size_t)(n0 + colw) * 2048 + s0 + 8] = v1;
    __syncthreads();
  }
}

// ---------------- sync helpers ----------------
__device__ __forceinline__ void post_ctr(unsigned* c)
{
  __syncthreads();   // all waves' stores drained (vmcnt(0) at barrier)
  if (threadIdx.x == 0) {
    __threadfence();
    __hip_atomic_fetch_add(c, 1u, __ATOMIC_RELEASE, __HIP_MEMORY_SCOPE_AGENT);
  }
}
__device__ __forceinline__ void wait_ctr(const unsigned* c, unsigned tgt)
{
  if (threadIdx.x == 0)
    while (__hip_atomic_load(c, __ATOMIC_ACQUIRE, __HIP_MEMORY_SCOPE_AGENT) < tgt)
      __builtin_amdgcn_s_sleep(8);
  __syncthreads();
}
__device__ __forceinline__ int tri_m(int q)
{
  int m = 0;
  while ((m + 1) * (m + 2) / 2 <= q) ++m;
  return m;
}

// ---------------- mega: whole post-prep pipeline, work-stealing queue --------
// Queue (1056 items, deps strictly on earlier items -> deadlock-free for any
// number of resident blocks; blocks grab items in order via sync[0]):
//  [0,16)      wct tiles                 -> post sync[1]
//  [16,272)    QK tiles                  -> post sync[2]
//  [272,400)   V' tiles   (wait s1==16)  -> post sync[3]
//  [400,544)   sc tiles   (wait s1,s2; last 15 z=0 m=6,7 also s3)
//                                        -> post sync[8+z*8+m]   (cnt_zm)
//  [544,800)   softmax 32-row items (wait cnt_zm[z,m]==m+1)
//                                        -> post sync[40+z*8+m]  (cnt_sm)
//  [800,992)   pv tiles   (wait s3==128 && cnt_sm[z,m0i]==8) -> post sync[4]
//  [992,1056)  add items  (wait s4==192)
__global__ __launch_bounds__(512, 2)
void mega(const unsigned short* __restrict__ xb,
          const unsigned short* __restrict__ wqb, const unsigned short* __restrict__ wkb,
          const unsigned short* __restrict__ opT, const unsigned short* __restrict__ vtb,
          unsigned short* __restrict__ wctb,
          unsigned short* __restrict__ Q, unsigned short* __restrict__ Kb,
          unsigned short* __restrict__ VT, unsigned short* __restrict__ SP,
          float* __restrict__ out, float* __restrict__ partial,
          unsigned* __restrict__ sync)
{
  const int tid = threadIdx.x;
  __shared__ __align__(16) char smem[131072];
  __shared__ unsigned s_idx;
  __shared__ float redm[2][4], reds[2][4];

  for (;;) {
    if (tid == 0)
      s_idx = __hip_atomic_fetch_add(&sync[0], 1u, __ATOMIC_RELAXED, __HIP_MEMORY_SCOPE_AGENT);
    __syncthreads();
    const unsigned idx = s_idx;
    if (idx >= 1056u) break;

    if (idx < 16u) {
      // ---- wct tile
      const int m0 = ((int)idx >> 2) * 256, n0 = ((int)idx & 3) * 256;
      f32x4 acc[8][4] = {};
      kloop8p(opT + (size_t)m0 * 1024, vtb + (size_t)n0 * 1024, 1024, 1024, 16, smem, acc);
      __syncthreads();
      epi_bf16(acc, wctb, 1024, m0, n0, smem);
      post_ctr(&sync[1]);
    } else if (idx < 272u) {
      // ---- QK tile
      do_qk((int)idx - 16, xb, wqb, wkb, Q, Kb, smem);
      post_ctr(&sync[2]);
    } else if (idx < 400u) {
      // ---- V' tile
      wait_ctr(&sync[1], 16u);
      do_vp((int)idx - 272, xb, wctb, VT, smem);
      post_ctr(&sync[3]);
    } else if (idx < 544u) {
      // ---- sc tile
      const int s = (int)idx - 400;
      int z, m, n; bool defer = false;
      if (s < 108)      { z = 1 + s / 36; const int q = s % 36; m = tri_m(q); n = q - m * (m + 1) / 2; }
      else if (s < 129) { z = 0; const int q = s - 108; m = tri_m(q); n = q - m * (m + 1) / 2; }  // m 0..5
      else              { z = 0; const int d = s - 129; if (d < 7) { m = 6; n = d; } else { m = 7; n = d - 7; } defer = true; }
      wait_ctr(&sync[1], 16u);            // wct done (vtb region overwrite)
      wait_ctr(&sync[2], 256u);           // all QK reads of wqb/wkb done
      if (defer) wait_ctr(&sync[3], 128u);// V' reads of wctb done
      f32x4 acc[8][4] = {};
      kloop8p(Q + (size_t)z * 2048 * 1024 + (size_t)(m * 256) * 1024,
              Kb + (size_t)z * 2048 * 1024 + (size_t)(n * 256) * 1024,
              1024, 1024, 16, smem, acc);
      __syncthreads();
      epi_bf16(acc, SP + (size_t)z * 2048 * 2048, 2048, m * 256, n * 256, smem);
      post_ctr(&sync[8 + z * 8 + m]);
    } else if (idx < 800u) {
      // ---- softmax item: 32 rows
      const int j = (int)idx - 544;
      const int z = j >> 6, mrow = (j & 63) >> 3;
      wait_ctr(&sync[8 + z * 8 + mrow], (unsigned)(mrow + 1));
      const int half = tid >> 8, t = tid & 255;
      const int w4 = (tid >> 6) & 3;
      for (int jj = 0; jj < 16; ++jj) {
        const int r  = j * 32 + jj * 2 + half;   // global row 0..8191
        const int rl = r & 2047;
        unsigned short* row = SP + (size_t)r * 2048;
        const int n    = rl + 1;
        const int nact = ((rl >> 8) + 1) << 5;
        const int c0   = t * 8;
        const bool act = t < nact;

        float v[8];
        float lmax = -1e30f;
        if (act) {
          const us8 pk = ((const us8*)row)[t];
#pragma unroll
          for (int q = 0; q < 8; ++q) {
            v[q] = bf2f(pk[q]);
            if (c0 + q < n) lmax = fmaxf(lmax, v[q]);
          }
        }
#pragma unroll
        for (int mm = 32; mm; mm >>= 1) lmax = fmaxf(lmax, __shfl_xor(lmax, mm, 64));
        if ((tid & 63) == 0) redm[half][w4] = lmax;
        __syncthreads();
        lmax = fmaxf(fmaxf(redm[half][0], redm[half][1]), fmaxf(redm[half][2], redm[half][3]));

        float e[8];
        float lsum = 0.f;
        if (act) {
#pragma unroll
          for (int q = 0; q < 8; ++q) {
            const float ev = (c0 + q < n) ? __expf((v[q] - lmax) * 0.03125f) : 0.f;
            e[q] = ev;
            lsum += ev;
          }
        }
#pragma unroll
        for (int mm = 32; mm; mm >>= 1) lsum += __shfl_xor(lsum, mm, 64);
        if ((tid & 63) == 0) reds[half][w4] = lsum;
        __syncthreads();
        lsum = reds[half][0] + reds[half][1] + reds[half][2] + reds[half][3];
        const float inv = 1.f / lsum;
        if (act) {
          us8 o;
#pragma unroll
          for (int q = 0; q < 8; ++q) o[q] = f2bf(e[q] * inv);
          ((us8*)row)[t] = o;
        }
      }
      post_ctr(&sync[40 + z * 8 + mrow]);
    } else if (idx < 992u) {
      // ---- pv tile (selective split-K, m0>=1024 only)
      const int p = (int)idx - 800;
      const int n0 = (p & 3) * 256;
      const int rest = p >> 2;
      const int y = rest % 12, z = rest / 12;
      int m0i, h;
      if (y < 4) { m0i = y; h = -1; }
      else       { m0i = 4 + ((y - 4) >> 1); h = (y - 4) & 1; }
      const int m0 = m0i * 256;
      int kb, NT;
      if (h < 0) { kb = 0; NT = (m0 + 256) >> 6; }
      else { const int Kh = (m0 + 256) >> 1; kb = h * Kh; NT = Kh >> 6; }
      wait_ctr(&sync[3], 128u);                         // VT complete
      wait_ctr(&sync[40 + z * 8 + m0i], 8u);            // sm rows of this m-block
      f32x4 acc[8][4] = {};
      kloop8p(SP + (size_t)z * 2048 * 2048 + (size_t)m0 * 2048 + kb,
              VT + (size_t)z * 1024 * 2048 + (size_t)n0 * 2048 + kb,
              2048, 2048, NT, smem, acc);
      __syncthreads();
      if (h == 1)
        epi_f32(acc, partial + (size_t)z * 1024 * 1024, 1024, m0 - 1024, n0, smem);
      else
        epi_f32(acc, out + (size_t)z * 2048 * 1024, 1024, m0, n0, smem);
      post_ctr(&sync[4]);
    } else {
      // ---- add item: out rows [1024,2048) per batch += partial
      const int a = (int)idx - 992;
      wait_ctr(&sync[4], 192u);
#pragma unroll 4
      for (int k = 0; k < 32; ++k) {
        const size_t i  = (size_t)a * 16384 + (size_t)k * 512 + tid;   // float4 idx < 1M
        const size_t z  = i >> 18;
        const size_t oi = i + (z + 1) * 262144;
        float4 va = ((const float4*)out)[oi];
        const float4 vb = ((const float4*)partial)[i];
        va.x += vb.x; va.y += vb.y; va.z += vb.z; va.w += vb.w;
        ((float4*)out)[oi] = va;
      }
      __syncthreads();
    }
  }
}

extern "C" void kernel_launch(void* const* d_in, const int* in_sizes, int n_in,
                              void* d_out, int out_size, void* d_ws, size_t ws_size,
                              hipStream_t stream)
{
  (void)in_sizes; (void)n_in; (void)out_size; (void)ws_size;
  // dict order: k, q, v, out_proj, x — f32 inputs, f32 output
  const float* wk_f = (const float*)d_in[0];
  const float* wq_f = (const float*)d_in[1];
  const float* wv_f = (const float*)d_in[2];
  const float* wo_f = (const float*)d_in[3];
  const float* x_f  = (const float*)d_in[4];
  float* out = (float*)d_out;

  // ws layout (98 MiB):
  char* p = (char*)d_ws;
  unsigned short* xb   = (unsigned short*)(p);                       // [0,16M)
  unsigned short* Q    = (unsigned short*)(p + ((size_t)16 << 20));  // [16,32M)
  unsigned short* Kb   = (unsigned short*)(p + ((size_t)32 << 20));  // [32,48M)
  unsigned short* VT   = (unsigned short*)(p + ((size_t)48 << 20));  // [48,64M): V'^T [B][j][s]
  unsigned short* SP   = (unsigned short*)(p + ((size_t)64 << 20));  // [64,96M): [B][S][S]
  unsigned short* wqb  = (unsigned short*)(p + ((size_t)64 << 20));  // aliases (dead before sc writes)
  unsigned short* wkb  = (unsigned short*)(p + ((size_t)66 << 20));
  unsigned short* vtb  = (unsigned short*)(p + ((size_t)68 << 20));  // v^T bf16
  unsigned short* wctb = (unsigned short*)(p + ((size_t)70 << 20));  // Wct = (v^T@out_proj)^T
  unsigned short* opT  = (unsigned short*)(p + ((size_t)96 << 20));  // [96,98M)
  float* partial = (float*)p;   // [0,16M): PV h=1 partial (xb dead by then)
  // sync counters: SP z=3, row 0, byte cols 2048.. — never written (causal skip
  // leaves z=3 m0=0 n0>=1024 tiles untouched) and never read (sm/pv touch only
  // cols < 256 of that row); prep writes [64,72M) + opT only.
  unsigned* sync = (unsigned*)(p + ((size_t)88 << 20) + 2048);

  dim3 blk256(256), blk512(512);

  // zero queue + dependency counters (72 u32; 512 B for slack)
  hipMemsetAsync(sync, 0, 512, stream);

  // conversions + transposes (x, wq, wk, v^T, out_proj^T)
  prep<<<dim3(12288), blk256, 0, stream>>>(x_f, wq_f, wk_f, wv_f, wo_f, xb, wqb, wkb, vtb, opT);

  // whole post-prep pipeline: persistent work-stealing queue, 256 blocks
  mega<<<dim3(256), blk512, 0, stream>>>(xb, wqb, wkb, opT, vtb, wctb,
                                         Q, Kb, VT, SP, out, partial, sync);
}